// Round 5
// baseline (12730.332 us; speedup 1.0000x reference)
//
#include <hip/hip_runtime.h>

#define TC 64            // timesteps per scan chunk
#define NCHUNK 8         // 8 * 64 = 512 steps

using bf16x8 = __attribute__((ext_vector_type(8))) short;
using f32x4  = __attribute__((ext_vector_type(4))) float;

__device__ __forceinline__ unsigned short f2bf(float f) {
  union { float f; unsigned int u; } v; v.f = f;
  unsigned int u = v.u;
  return (unsigned short)((u + 0x7fffu + ((u >> 16) & 1u)) >> 16);  // RNE
}

__device__ __forceinline__ unsigned long long ldU64(const void* p) {
  return __hip_atomic_load((const unsigned long long*)p, __ATOMIC_RELAXED, __HIP_MEMORY_SCOPE_AGENT);
}
__device__ __forceinline__ void stU64(void* p, unsigned long long v) {
  __hip_atomic_store((unsigned long long*)p, v, __ATOMIC_RELAXED, __HIP_MEMORY_SCOPE_AGENT);
}
__device__ __forceinline__ unsigned int ldU32(const void* p) {
  return __hip_atomic_load((const unsigned int*)p, __ATOMIC_RELAXED, __HIP_MEMORY_SCOPE_AGENT);
}
__device__ __forceinline__ void stU32(void* p, unsigned int v) {
  __hip_atomic_store((unsigned int*)p, v, __ATOMIC_RELAXED, __HIP_MEMORY_SCOPE_AGENT);
}

// ---------------------------------------------------------------------------
// sentinel: ws too small -> unmistakable output
// ---------------------------------------------------------------------------
__global__ void sentinel_k(float* out, int n) {
  int i = blockIdx.x * 256 + threadIdx.x;
  for (; i < n; i += gridDim.x * 256) out[i] = 12345.0f;
}

// ---------------------------------------------------------------------------
// Wh transpose: WhT[k][h] = Wh[h][k]   (1024 x 1024 fp32)
// ---------------------------------------------------------------------------
__global__ __launch_bounds__(1024) void transpose_wh(const float* __restrict__ Wh,
                                                     float* __restrict__ WhT) {
  __shared__ float t[32][33];
  const int bx = blockIdx.x * 32;  // k base
  const int by = blockIdx.y * 32;  // h base
  t[threadIdx.y][threadIdx.x] = Wh[(by + threadIdx.y) * 1024 + bx + threadIdx.x];
  __syncthreads();
  WhT[(bx + threadIdx.y) * 1024 + by + threadIdx.x] = t[threadIdx.x][threadIdx.y];
}

// ---------------------------------------------------------------------------
// GEMM1 (pure fp32): xp chunk.  XPc[(sc*64+b)*1024+n] = sum_k x[b][t0+sc][k]*Wi[n][k] + bi[n]
// M = 4096 rows (mm = b*64+sc), K=512, N=1024.  BM=BN=64, BK=16, 256 thr, 4x4/thread.
// ---------------------------------------------------------------------------
__global__ __launch_bounds__(256) void gemm1_f32(
    const float* __restrict__ x, const float* __restrict__ Wi,
    const float* __restrict__ bi_g, float* __restrict__ XPc, int t0)
{
  __shared__ float sA[16][68];
  __shared__ float sB[16][68];
  const int tid = threadIdx.x;
  const int m0 = blockIdx.x * 64;
  const int n0 = blockIdx.y * 64;
  const int tx = tid & 15, ty = tid >> 4;
  const int sm = tid & 63, kq = tid >> 6;

  float acc[4][4] = {};
  const int mm = m0 + sm;
  const int b = mm >> 6, sc = mm & 63;
  const float* arow = x + ((size_t)b * 512 + (t0 + sc)) * 512;
  const float* brow = Wi + (size_t)(n0 + sm) * 512;

  for (int kt = 0; kt < 512; kt += 16) {
    float4 va = *(const float4*)(arow + kt + (kq << 2));
    float4 vb = *(const float4*)(brow + kt + (kq << 2));
    sA[(kq << 2) + 0][sm] = va.x; sA[(kq << 2) + 1][sm] = va.y;
    sA[(kq << 2) + 2][sm] = va.z; sA[(kq << 2) + 3][sm] = va.w;
    sB[(kq << 2) + 0][sm] = vb.x; sB[(kq << 2) + 1][sm] = vb.y;
    sB[(kq << 2) + 2][sm] = vb.z; sB[(kq << 2) + 3][sm] = vb.w;
    __syncthreads();
    #pragma unroll
    for (int kk = 0; kk < 16; ++kk) {
      float4 a4 = *(const float4*)&sA[kk][ty << 2];
      float4 b4 = *(const float4*)&sB[kk][tx << 2];
      acc[0][0] += a4.x * b4.x; acc[0][1] += a4.x * b4.y; acc[0][2] += a4.x * b4.z; acc[0][3] += a4.x * b4.w;
      acc[1][0] += a4.y * b4.x; acc[1][1] += a4.y * b4.y; acc[1][2] += a4.y * b4.z; acc[1][3] += a4.y * b4.w;
      acc[2][0] += a4.z * b4.x; acc[2][1] += a4.z * b4.y; acc[2][2] += a4.z * b4.z; acc[2][3] += a4.z * b4.w;
      acc[3][0] += a4.w * b4.x; acc[3][1] += a4.w * b4.y; acc[3][2] += a4.w * b4.z; acc[3][3] += a4.w * b4.w;
    }
    __syncthreads();
  }
  float4 bv = *(const float4*)&bi_g[n0 + (tx << 2)];
  #pragma unroll
  for (int i = 0; i < 4; ++i) {
    const int mo = m0 + (ty << 2) + i;
    const int ob = mo >> 6, osc = mo & 63;
    float4 o;
    o.x = acc[i][0] + bv.x; o.y = acc[i][1] + bv.y;
    o.z = acc[i][2] + bv.z; o.w = acc[i][3] + bv.w;
    *(float4*)&XPc[(size_t)((osc << 6) + ob) * 1024 + n0 + (tx << 2)] = o;
  }
}

// ---------------------------------------------------------------------------
// Recurrent scan chunk (TC steps). 256 blocks x 256 thr, regular launch.
// Co-residency: 66 KiB LDS/block caps residency at 2 blocks/CU, so all 256
// blocks are simultaneously resident in every feasible dispatch packing.
// 4 groups x 16 batches. Block (g, hc): owns 16 h x 16 b. ONE barrier/step.
// HT[2][1024][64] holds PRE-LN inner; LN+tanh applied (deterministically,
// redundantly) at staging time using SP stat-partials summed in a fixed tree.
// All cross-block exchange via relaxed AGENT atomics (L1-bypass, sc1) -> no
// cache-wide invalidates -> WhT stays L2-hot across all 512 steps.
// LDS swizzle: float2-col c2 stored at col (c2 ^ ((k>>1)&7)) -> exactly
// 4 accesses/bank (the ds b64 floor) on both write and read sides.
// ---------------------------------------------------------------------------
__global__ __launch_bounds__(256, 1) void rnn_scan(
    const float* __restrict__ XPc, const float* __restrict__ WhT,
    const float* __restrict__ bh_g, const float* __restrict__ lng,
    const float* __restrict__ lnb, float* __restrict__ HT,
    unsigned short* __restrict__ HRMb, float* __restrict__ SP,
    unsigned int* __restrict__ flags, int t0)
{
  __shared__ float hs[1024 * 16];       // [k][16 b] fp32, float2-col xor-swizzle
  __shared__ float swa[4][16], swb[4][16];
  __shared__ float ssm[16], ssr[16];    // per-b mu, rstd

  const int tid = threadIdx.x;
  const int blk = blockIdx.x;
  const int g = blk >> 6, hc = blk & 63;
  const int b0 = g << 4, h0 = hc << 4;
  const int w = tid >> 6;               // wave id = h-quad
  const int l = tid & 63;
  const int btq = l >> 4, ks = l & 15;
  const int hi = ks & 3, bi = ks >> 2;
  const int own_h = h0 + (w << 2) + hi;
  const int own_b = b0 + (btq << 2) + bi;
  const int ib = (btq << 2) + bi;       // own_b - b0
  const float bh_v = bh_g[own_h];
  const float g_v = lng[own_h], be_v = lnb[own_h];
  const int sr = tid >> 2, c2s = tid & 3;   // staging coords
  const int b16 = tid >> 4, pl = tid & 15;  // ss-tree coords
  unsigned int* myflags = flags + (g << 6);

  for (int ts = 0; ts < TC; ++ts) {
    const int t = t0 + ts;

    if (t > 0) {
      // ---- deterministic stat reduction for step t-1 ----
      const float* SPo = SP + (((t - 1) & 1) << 13);
      float s1 = 0.f, s2 = 0.f;
      #pragma unroll
      for (int q = 0; q < 4; ++q) {
        unsigned long long u = ldU64(&SPo[((size_t)(b0 + b16) << 7) + ((pl + (q << 4)) << 1)]);
        s1 += __uint_as_float((unsigned int)u);
        s2 += __uint_as_float((unsigned int)(u >> 32));
      }
      s1 += __shfl_xor(s1, 1); s2 += __shfl_xor(s2, 1);
      s1 += __shfl_xor(s1, 2); s2 += __shfl_xor(s2, 2);
      s1 += __shfl_xor(s1, 4); s2 += __shfl_xor(s2, 4);
      s1 += __shfl_xor(s1, 8); s2 += __shfl_xor(s2, 8);
      if (pl == 0) {
        float mu = s1 * (1.0f / 1024.0f);
        float var = s2 * (1.0f / 1024.0f) - mu * mu;
        ssm[b16] = mu;
        ssr[b16] = 1.0f / sqrtf(var + 1e-5f);
      }
      __syncthreads();

      const float* HTo = HT + (((t - 1) & 1) << 16);
      // ---- own-element h(t-1) -> HRMb (bf16 history for output GEMM) ----
      {
        float iv = __uint_as_float(ldU32(&HTo[(own_h << 6) + own_b]));
        float hv = tanhf((iv - ssm[ib]) * ssr[ib] * g_v + be_v);
        HRMb[(size_t)(((t - 1) << 6) + own_b) * 1024 + own_h] = f2bf(hv);
      }
      // ---- stage h(t-1) = tanh(LN(inner)) into LDS ----
      #pragma unroll 2
      for (int p = 0; p < 16; ++p) {
        int k = (p << 6) + sr;
        int sw = (k >> 1) & 7;
        float gk = lng[k], bek = lnb[k];
        #pragma unroll
        for (int s = 0; s < 2; ++s) {
          int c2 = c2s + (s << 2);
          unsigned long long u = ldU64(&HTo[(k << 6) + b0 + (c2 << 1)]);
          float x0 = __uint_as_float((unsigned int)u);
          float x1 = __uint_as_float((unsigned int)(u >> 32));
          int bb = c2 << 1;
          float h0v = tanhf((x0 - ssm[bb]) * ssr[bb] * gk + bek);
          float h1v = tanhf((x1 - ssm[bb + 1]) * ssr[bb + 1] * gk + bek);
          *(float2*)&hs[(k << 4) + ((c2 ^ sw) << 1)] = make_float2(h0v, h1v);
        }
      }
    } else {
      for (int p = 0; p < 16; ++p) {
        int k = (p << 6) + sr;
        int sw = (k >> 1) & 7;
        #pragma unroll
        for (int s = 0; s < 2; ++s) {
          int c2 = c2s + (s << 2);
          *(float2*)&hs[(k << 4) + ((c2 ^ sw) << 1)] = make_float2(0.f, 0.f);
        }
      }
    }
    __syncthreads();

    // ---- GEMM: inner partial over this lane's k-slice (k = 16j + ks) ----
    float acc[4][4] = {};
    const float* wp = WhT + h0 + (w << 2);
    #pragma unroll 4
    for (int j = 0; j < 64; ++j) {
      int k = (j << 4) + ks;
      int sw = (k >> 1) & 7;
      float4 wv = *(const float4*)&wp[(size_t)k << 10];
      int cA = ((btq << 1) ^ sw) << 1;
      int cB = (((btq << 1) | 1) ^ sw) << 1;
      float2 av0 = *(const float2*)&hs[(k << 4) + cA];
      float2 av1 = *(const float2*)&hs[(k << 4) + cB];
      acc[0][0] += wv.x * av0.x; acc[0][1] += wv.x * av0.y; acc[0][2] += wv.x * av1.x; acc[0][3] += wv.x * av1.y;
      acc[1][0] += wv.y * av0.x; acc[1][1] += wv.y * av0.y; acc[1][2] += wv.y * av1.x; acc[1][3] += wv.y * av1.y;
      acc[2][0] += wv.z * av0.x; acc[2][1] += wv.z * av0.y; acc[2][2] += wv.z * av1.x; acc[2][3] += wv.z * av1.y;
      acc[3][0] += wv.w * av0.x; acc[3][1] += wv.w * av0.y; acc[3][2] += wv.w * av1.x; acc[3][3] += wv.w * av1.y;
    }
    // ---- reduce over ks (lane bits 0..3) ----
    #pragma unroll
    for (int i2 = 0; i2 < 4; ++i2)
      #pragma unroll
      for (int j2 = 0; j2 < 4; ++j2) {
        float v = acc[i2][j2];
        v += __shfl_xor(v, 1); v += __shfl_xor(v, 2);
        v += __shfl_xor(v, 4); v += __shfl_xor(v, 8);
        acc[i2][j2] = v;
      }
    // lane ks claims element (hi = ks&3, bi = ks>>2): val = acc[hi][bi]
    float val;
    switch (ks) {
      case 0:  val = acc[0][0]; break; case 1:  val = acc[1][0]; break;
      case 2:  val = acc[2][0]; break; case 3:  val = acc[3][0]; break;
      case 4:  val = acc[0][1]; break; case 5:  val = acc[1][1]; break;
      case 6:  val = acc[2][1]; break; case 7:  val = acc[3][1]; break;
      case 8:  val = acc[0][2]; break; case 9:  val = acc[1][2]; break;
      case 10: val = acc[2][2]; break; case 11: val = acc[3][2]; break;
      case 12: val = acc[0][3]; break; case 13: val = acc[1][3]; break;
      case 14: val = acc[2][3]; break; default: val = acc[3][3]; break;
    }
    val += bh_v + XPc[(size_t)((ts << 6) + own_b) * 1024 + own_h];

    // ---- per-(b, block) stat partials over this block's 16 h ----
    float sv = val, sq = val * val;
    sv += __shfl_xor(sv, 1); sq += __shfl_xor(sq, 1);
    sv += __shfl_xor(sv, 2); sq += __shfl_xor(sq, 2);
    if ((l & 3) == 0) { swa[w][ib] = sv; swb[w][ib] = sq; }
    __syncthreads();
    if (tid < 16) {
      float s1 = swa[0][tid] + swa[1][tid] + swa[2][tid] + swa[3][tid];
      float s2 = swb[0][tid] + swb[1][tid] + swb[2][tid] + swb[3][tid];
      unsigned long long u = ((unsigned long long)__float_as_uint(s2) << 32) | __float_as_uint(s1);
      stU64(&SP[((size_t)(t & 1) << 13) + ((size_t)(b0 + tid) << 7) + (hc << 1)], u);
    }
    // ---- own-element inner(t) -> HT ----
    stU32(&HT[((size_t)(t & 1) << 16) + (own_h << 6) + own_b], __float_as_uint(val));
    __syncthreads();  // compiler drains vmcnt before s_barrier -> stores done

    // ---- group barrier (phase t+1): flag-array + wave poll, no cache inv ----
    if (tid == 0) stU32(&myflags[hc], (unsigned int)(t + 1));
    if (tid < 64) {
      unsigned int tgt = (unsigned int)(t + 1);
      int gd = 0; bool done = false;
      do {
        unsigned int v = ldU32(&myflags[tid]);
        done = (bool)__all((int)(v >= tgt));
      } while (!done && (++gd < (1 << 18)));
    }
    asm volatile("" ::: "memory");  // no data loads hoisted above the poll
    __syncthreads();
  }

  // ---- post-loop: h(t_last) -> HRMb (next chunk rewrites identically) ----
  {
    const int tl = t0 + TC - 1;
    const float* SPo = SP + (((size_t)(tl & 1)) << 13);
    float s1 = 0.f, s2 = 0.f;
    #pragma unroll
    for (int q = 0; q < 4; ++q) {
      unsigned long long u = ldU64(&SPo[((size_t)(b0 + b16) << 7) + ((pl + (q << 4)) << 1)]);
      s1 += __uint_as_float((unsigned int)u);
      s2 += __uint_as_float((unsigned int)(u >> 32));
    }
    s1 += __shfl_xor(s1, 1); s2 += __shfl_xor(s2, 1);
    s1 += __shfl_xor(s1, 2); s2 += __shfl_xor(s2, 2);
    s1 += __shfl_xor(s1, 4); s2 += __shfl_xor(s2, 4);
    s1 += __shfl_xor(s1, 8); s2 += __shfl_xor(s2, 8);
    if (pl == 0) {
      float mu = s1 * (1.0f / 1024.0f);
      float var = s2 * (1.0f / 1024.0f) - mu * mu;
      ssm[b16] = mu;
      ssr[b16] = 1.0f / sqrtf(var + 1e-5f);
    }
    __syncthreads();
    const float* HTo = HT + (((size_t)(tl & 1)) << 16);
    float iv = __uint_as_float(ldU32(&HTo[(own_h << 6) + own_b]));
    float hv = tanhf((iv - ssm[ib]) * ssr[ib] * g_v + be_v);
    HRMb[(size_t)((tl << 6) + own_b) * 1024 + own_h] = f2bf(hv);
  }
}

// ---------------------------------------------------------------------------
// GEMM2 (bf16 MFMA): out[m][n] = sum_k HRMb[m][k]*bf16(Wo[n][k]) + bo[n]
// M=32768, K=1024, N=512. 128x128 tile, BK=32, 256 thr (4 waves 2x2).
// ---------------------------------------------------------------------------
__global__ __launch_bounds__(256) void gemm2_bf16(
    const unsigned short* __restrict__ A, const float* __restrict__ Wo,
    const float* __restrict__ bo_g, float* __restrict__ C)
{
  __shared__ unsigned short sA[128][40];
  __shared__ unsigned short sB[128][40];
  const int tid = threadIdx.x;
  const int m0 = blockIdx.x * 128;
  const int n0 = blockIdx.y * 128;
  const int l = tid & 63, w = tid >> 6;
  const int wm = w >> 1, wn = w & 1;
  const int fr = l & 15, koff = (l >> 4) << 3;
  const int srow = tid >> 1, shalf = tid & 1;

  f32x4 acc[4][4] = {};

  for (int kt = 0; kt < 1024; kt += 32) {
    {
      const uint4* ap = reinterpret_cast<const uint4*>(A + (size_t)(m0 + srow) * 1024 + kt + (shalf << 4));
      uint4 a0 = ap[0], a1 = ap[1];
      *(uint4*)&sA[srow][(shalf << 4) + 0] = a0;
      *(uint4*)&sA[srow][(shalf << 4) + 8] = a1;
    }
    {
      const float4* bp = reinterpret_cast<const float4*>(Wo + (size_t)(n0 + srow) * 1024 + kt + (shalf << 4));
      unsigned int arr[8];
      #pragma unroll
      for (int i = 0; i < 4; ++i) {
        float4 v = bp[i];
        arr[2 * i + 0] = (unsigned)f2bf(v.x) | ((unsigned)f2bf(v.y) << 16);
        arr[2 * i + 1] = (unsigned)f2bf(v.z) | ((unsigned)f2bf(v.w) << 16);
      }
      *(uint4*)&sB[srow][(shalf << 4) + 0] = *(uint4*)&arr[0];
      *(uint4*)&sB[srow][(shalf << 4) + 8] = *(uint4*)&arr[4];
    }
    __syncthreads();
    bf16x8 af[4];
    #pragma unroll
    for (int mi = 0; mi < 4; ++mi)
      af[mi] = *(const bf16x8*)&sA[wm * 64 + mi * 16 + fr][koff];
    #pragma unroll
    for (int ni = 0; ni < 4; ++ni) {
      bf16x8 bf = *(const bf16x8*)&sB[wn * 64 + ni * 16 + fr][koff];
      #pragma unroll
      for (int mi = 0; mi < 4; ++mi)
        acc[mi][ni] = __builtin_amdgcn_mfma_f32_16x16x32_bf16(af[mi], bf, acc[mi][ni], 0, 0, 0);
    }
    __syncthreads();
  }
  #pragma unroll
  for (int ni = 0; ni < 4; ++ni) {
    const int n = n0 + wn * 64 + ni * 16 + fr;
    const float bon = bo_g[n];
    #pragma unroll
    for (int mi = 0; mi < 4; ++mi) {
      #pragma unroll
      for (int r = 0; r < 4; ++r) {
        const int m = m0 + wm * 64 + mi * 16 + ((l >> 4) << 2) + r;
        C[(size_t)m * 512 + n] = acc[mi][ni][r] + bon;
      }
    }
  }
}

// ---------------------------------------------------------------------------
extern "C" void kernel_launch(void* const* d_in, const int* in_sizes, int n_in,
                              void* d_out, int out_size, void* d_ws, size_t ws_size,
                              hipStream_t stream)
{
  const float* x   = (const float*)d_in[0];
  const float* Wh  = (const float*)d_in[1];
  const float* bh  = (const float*)d_in[2];
  const float* Wi  = (const float*)d_in[3];
  const float* bi  = (const float*)d_in[4];
  const float* Wo  = (const float*)d_in[5];
  const float* bo  = (const float*)d_in[6];
  const float* lng = (const float*)d_in[7];
  const float* lnb = (const float*)d_in[8];
  float* out = (float*)d_out;

  char* w = (char*)d_ws;
  const size_t XPC_OFF = 0;           // [64][64][1024] f32      16 MiB (chunk, reused)
  const size_t HRM_OFF = 16777216;    // [32768][1024] bf16      64 MiB
  const size_t WHT_OFF = 83886080;    // [1024][1024]  f32        4 MiB
  const size_t HT_OFF  = 88080384;    // [2][1024][64] f32      512 KiB (pre-LN inner)
  const size_t SP_OFF  = 88604672;    // [2][64][64]   float2    64 KiB
  const size_t FL_OFF  = 88670208;    // flags                    4 KiB
  const size_t NEEDED  = 88674304;
  if (ws_size < NEEDED) {
    hipLaunchKernelGGL(sentinel_k, dim3(256), dim3(256), 0, stream, out, out_size);
    return;
  }

  float* XPC = (float*)(w + XPC_OFF);
  unsigned short* HRMb = (unsigned short*)(w + HRM_OFF);
  float* WHT = (float*)(w + WHT_OFF);
  float* HT  = (float*)(w + HT_OFF);
  float* SP  = (float*)(w + SP_OFF);
  unsigned int* FLAGS = (unsigned int*)(w + FL_OFF);

  hipMemsetAsync(w + FL_OFF, 0, 4096, stream);
  hipLaunchKernelGGL(transpose_wh, dim3(32, 32), dim3(32, 32), 0, stream, Wh, WHT);

  for (int c = 0; c < NCHUNK; ++c) {
    const int t0 = c * TC;
    hipLaunchKernelGGL(gemm1_f32, dim3(64, 16), dim3(256), 0, stream, x, Wi, bi, XPC, t0);
    hipLaunchKernelGGL(rnn_scan, dim3(256), dim3(256), 0, stream,
                       XPC, WHT, bh, lng, lnb, HT, HRMb, SP, FLAGS, t0);
  }
  hipLaunchKernelGGL(gemm2_bf16, dim3(256, 4), dim3(256), 0, stream, HRMb, Wo, bo, out);
}